// Round 1
// baseline (317.253 us; speedup 1.0000x reference)
//
#include <hip/hip_runtime.h>

typedef __bf16 bf16x8 __attribute__((ext_vector_type(8)));
typedef float  f32x4  __attribute__((ext_vector_type(4)));

__device__ __forceinline__ f32x4 mfma_bf16(bf16x8 a, bf16x8 b, f32x4 c) {
  return __builtin_amdgcn_mfma_f32_16x16x32_bf16(a, b, c, 0, 0, 0);
}

// ---------------------------------------------------------------------------
// Pack f32 weight W (N x K, row-major) into MFMA B-operand fragment order:
// out[((kt*NT+nt)*64 + lane)*8 + e] = W[nt*16 + (lane&15)][kt*32 + (lane>>4)*8 + e]
// Zero-pads n >= N, k >= K.
// ---------------------------------------------------------------------------
__global__ void pack_w(const float* __restrict__ W, __bf16* __restrict__ out,
                       int N, int K, int NT) {
  int bx = blockIdx.x;
  int nt = bx % NT, kt = bx / NT;
  int lane = threadIdx.x;
  int n = nt * 16 + (lane & 15);
  int k0 = kt * 32 + (lane >> 4) * 8;
  bf16x8 v;
#pragma unroll
  for (int e = 0; e < 8; ++e) {
    int k = k0 + e;
    float x = (n < N && k < K) ? W[(size_t)n * K + k] : 0.f;
    v[e] = (__bf16)x;
  }
  *reinterpret_cast<bf16x8*>(out + ((size_t)bx * 64 + lane) * 8) = v;
}

// ---------------------------------------------------------------------------
// Main MFMA GEMM: C(M x Np) = epilogue(A @ W^T + bias)
// Block tile 64 x 128, 4 waves (2x2), wave tile 32 x 64 (2 m-frags x 4 n-frags)
// A: row-major, f32 (inline converted) or bf16. B: packed fragments (pack_w).
// MODE 0: store relu->bf16 (o0) and mask->bf16 (o1), ld = Nact
// MODE 1: store mask->bf16 (o0)
// MODE 2: store relu->bf16 (o0)
// MODE 3: store f32 (o0), cols < Nact, ldc = Nact
// MODE 4: zsum special: o0=z_geo f32, o1=zn f32, o2=z_npi f32, o3=zn bf16,
//         extra=z_npi1 row (Nact==128, single col-block)
// ---------------------------------------------------------------------------
template <bool AF32, int MODE>
__global__ __launch_bounds__(256) void gemm_mfma(
    const void* __restrict__ Aptr, int lda, int Kact, int KT,
    const __bf16* __restrict__ Bp, int NT, const float* __restrict__ bias,
    int Nact, void* __restrict__ o0, void* __restrict__ o1,
    void* __restrict__ o2, void* __restrict__ o3,
    const float* __restrict__ extra) {
  __shared__ __bf16 Alds[64][40];   // stride 40 bf16 = 80B (16B-aligned, ~2-way banks)
  __shared__ float red[2][64];
  int tid = threadIdx.x;
  int lane = tid & 63, wid = tid >> 6;
  int wr = wid >> 1, wc = wid & 1;
  int bm = blockIdx.x, bn = blockIdx.y;
  int rowBase = bm * 64;
  int sr = tid >> 2, sc = (tid & 3) * 8;
  const float* Af = (const float*)Aptr;
  const __bf16* Ab = (const __bf16*)Aptr;
  f32x4 acc[2][4] = {};

  for (int kt = 0; kt < KT; ++kt) {
    int gk = kt * 32 + sc;
    bf16x8 v;
    if (AF32) {
      if (gk < Kact) {  // Kact % 8 == 0 for all uses -> whole-group validity
        const float* src = Af + (size_t)(rowBase + sr) * lda + gk;
        float4 x0 = *(const float4*)src;
        float4 x1 = *(const float4*)(src + 4);
        v[0] = (__bf16)x0.x; v[1] = (__bf16)x0.y; v[2] = (__bf16)x0.z; v[3] = (__bf16)x0.w;
        v[4] = (__bf16)x1.x; v[5] = (__bf16)x1.y; v[6] = (__bf16)x1.z; v[7] = (__bf16)x1.w;
      } else {
#pragma unroll
        for (int e = 0; e < 8; ++e) v[e] = (__bf16)0.f;
      }
    } else {
      v = *reinterpret_cast<const bf16x8*>(Ab + (size_t)(rowBase + sr) * lda + gk);
    }
    *reinterpret_cast<bf16x8*>(&Alds[sr][sc]) = v;
    __syncthreads();

    int arow = wr * 32 + (lane & 15);
    int ak = (lane >> 4) * 8;
    bf16x8 a0 = *reinterpret_cast<const bf16x8*>(&Alds[arow][ak]);
    bf16x8 a1v = *reinterpret_cast<const bf16x8*>(&Alds[arow + 16][ak]);
#pragma unroll
    for (int n = 0; n < 4; ++n) {
      int nt = bn * 8 + wc * 4 + n;
      bf16x8 bv = *reinterpret_cast<const bf16x8*>(
          Bp + (((size_t)kt * NT + nt) * 64 + lane) * 8);
      acc[0][n] = mfma_bf16(a0, bv, acc[0][n]);
      acc[1][n] = mfma_bf16(a1v, bv, acc[1][n]);
    }
    __syncthreads();
  }

  // ---- epilogue: C element (row, col): row = (lane>>4)*4 + reg, col = lane&15
  int colBase = bn * 128 + wc * 64;
  int rowW = rowBase + wr * 32;
  int q4 = (lane >> 4) * 4;

  if (MODE == 4) {
    float zs[2][4][4];
    float* zgeo = (float*)o0;
    float* znf = (float*)o1;
    float* znpi = (float*)o2;
    __bf16* znb = (__bf16*)o3;
#pragma unroll
    for (int m = 0; m < 2; ++m)
#pragma unroll
      for (int n = 0; n < 4; ++n) {
        int col = colBase + n * 16 + (lane & 15);
        float bb = bias[col];
        float zv = extra[col];
#pragma unroll
        for (int j = 0; j < 4; ++j) {
          int row = rowW + m * 16 + q4 + j;
          float zg = acc[m][n][j] + bb;
          zgeo[(size_t)row * 128 + col] = zg;
          znpi[(size_t)row * 128 + col] = zv;
          zs[m][n][j] = zg + zv;
        }
      }
    // row-wise sum of squares: reduce 16 cols across the quarter, both wc via LDS
#pragma unroll
    for (int m = 0; m < 2; ++m)
#pragma unroll
      for (int j = 0; j < 4; ++j) {
        float pp = 0.f;
#pragma unroll
        for (int n = 0; n < 4; ++n) pp += zs[m][n][j] * zs[m][n][j];
        pp += __shfl_xor(pp, 1);
        pp += __shfl_xor(pp, 2);
        pp += __shfl_xor(pp, 4);
        pp += __shfl_xor(pp, 8);
        if ((lane & 15) == 0) red[wc][wr * 32 + m * 16 + q4 + j] = pp;
      }
    __syncthreads();
#pragma unroll
    for (int m = 0; m < 2; ++m)
#pragma unroll
      for (int n = 0; n < 4; ++n) {
        int col = colBase + n * 16 + (lane & 15);
#pragma unroll
        for (int j = 0; j < 4; ++j) {
          int rl = wr * 32 + m * 16 + q4 + j;
          int row = rowBase + rl;
          float ss = red[0][rl] + red[1][rl];
          float rn = 1.f / fmaxf(sqrtf(ss), 1e-12f);
          float z = zs[m][n][j] * rn;
          znf[(size_t)row * 128 + col] = z;
          znb[(size_t)row * 128 + col] = (__bf16)z;
        }
      }
  } else {
#pragma unroll
    for (int m = 0; m < 2; ++m)
#pragma unroll
      for (int n = 0; n < 4; ++n) {
        int col = colBase + n * 16 + (lane & 15);
        float bb = (col < Nact) ? bias[col] : 0.f;
#pragma unroll
        for (int j = 0; j < 4; ++j) {
          int row = rowW + m * 16 + q4 + j;
          float h = acc[m][n][j] + bb;
          if (MODE == 0) {
            ((__bf16*)o0)[(size_t)row * Nact + col] = (__bf16)fmaxf(h, 0.f);
            ((__bf16*)o1)[(size_t)row * Nact + col] = (__bf16)(h > 0.f ? 1.f : 0.f);
          } else if (MODE == 1) {
            ((__bf16*)o0)[(size_t)row * Nact + col] = (__bf16)(h > 0.f ? 1.f : 0.f);
          } else if (MODE == 2) {
            ((__bf16*)o0)[(size_t)row * Nact + col] = (__bf16)fmaxf(h, 0.f);
          } else {
            if (col < Nact) ((float*)o0)[(size_t)row * Nact + col] = h;
          }
        }
      }
  }
}

// ---------------------------------------------------------------------------
// Gpart[z][i][j] = sum_{b in chunk z} m2[b][i] * m1[b][j]   (64x64 tile/block)
// Masks are 0/1 bf16 -> MFMA result exact (f32 integer accumulation).
// ---------------------------------------------------------------------------
__global__ __launch_bounds__(256) void gemm_masks(
    const __bf16* __restrict__ m2, const __bf16* __restrict__ m1,
    float* __restrict__ Gpart) {
  __shared__ __bf16 Aft[64][40];  // [i][k] = m2[b0+k][ibase+i]
  __shared__ __bf16 Bft[64][40];  // [j][k] = m1[b0+k][jbase+j]
  int tid = threadIdx.x;
  int lane = tid & 63, wid = tid >> 6;
  int wr = wid >> 1, wc = wid & 1;
  int ibase = blockIdx.x * 64, jbase = blockIdx.y * 64;
  int b0 = blockIdx.z * 1024;
  int skk = tid >> 3, si0 = (tid & 7) * 8;
  f32x4 acc[2][2] = {};
  for (int c = 0; c < 32; ++c) {
    int bb = b0 + c * 32 + skk;
    bf16x8 va = *reinterpret_cast<const bf16x8*>(m2 + (size_t)bb * 256 + ibase + si0);
    bf16x8 vb = *reinterpret_cast<const bf16x8*>(m1 + (size_t)bb * 256 + jbase + si0);
#pragma unroll
    for (int e = 0; e < 8; ++e) {
      Aft[si0 + e][skk] = va[e];
      Bft[si0 + e][skk] = vb[e];
    }
    __syncthreads();
    int ar = wr * 32 + (lane & 15);
    int br = wc * 32 + (lane & 15);
    int k8 = (lane >> 4) * 8;
    bf16x8 a0 = *reinterpret_cast<const bf16x8*>(&Aft[ar][k8]);
    bf16x8 a1v = *reinterpret_cast<const bf16x8*>(&Aft[ar + 16][k8]);
    bf16x8 b0v = *reinterpret_cast<const bf16x8*>(&Bft[br][k8]);
    bf16x8 b1v = *reinterpret_cast<const bf16x8*>(&Bft[br + 16][k8]);
    acc[0][0] = mfma_bf16(a0, b0v, acc[0][0]);
    acc[0][1] = mfma_bf16(a0, b1v, acc[0][1]);
    acc[1][0] = mfma_bf16(a1v, b0v, acc[1][0]);
    acc[1][1] = mfma_bf16(a1v, b1v, acc[1][1]);
    __syncthreads();
  }
  float* dst = Gpart + (size_t)blockIdx.z * 65536;
  int q4 = (lane >> 4) * 4;
#pragma unroll
  for (int m = 0; m < 2; ++m)
#pragma unroll
    for (int n = 0; n < 2; ++n)
#pragma unroll
      for (int j = 0; j < 4; ++j) {
        int gi = ibase + wr * 32 + m * 16 + q4 + j;
        int gj = jbase + wc * 32 + n * 16 + (lane & 15);
        dst[(size_t)gi * 256 + gj] = acc[m][n][j];
      }
}

__global__ void reduce_G(const float* __restrict__ Gpart, float* __restrict__ G) {
  int i = blockIdx.x * 256 + threadIdx.x;
  float s = 0.f;
#pragma unroll
  for (int z = 0; z < 16; ++z) s += Gpart[(size_t)z * 65536 + i];
  G[i] = s * (1.f / 16384.f);
}

// ---------------------------------------------------------------------------
// Small f32 GEMM: C[M x N] = (A (.* A2)) @ B ; A row-major lda, B row-major ldb
// 64x64 tile, 256 threads, 4x4 per-thread microtile.
// ---------------------------------------------------------------------------
__global__ __launch_bounds__(256) void small_gemm(
    const float* __restrict__ A, const float* __restrict__ A2, int lda,
    const float* __restrict__ Bm, int ldb, float* __restrict__ C, int ldc,
    int M, int N, int K) {
  __shared__ float As[64][17];
  __shared__ float Bs[16][65];
  int t = threadIdx.x;
  int tx = t & 15, ty = t >> 4;
  int m0 = blockIdx.y * 64, n0 = blockIdx.x * 64;
  float acc[4][4] = {};
  for (int k0 = 0; k0 < K; k0 += 16) {
#pragma unroll
    for (int i = 0; i < 4; ++i) {
      int idx = t * 4 + i;
      int r = idx >> 4, kk = idx & 15;
      int gm = m0 + r, gk = k0 + kk;
      float v = (gm < M && gk < K) ? A[(size_t)gm * lda + gk] : 0.f;
      if (A2 && gm < M && gk < K) v *= A2[(size_t)gm * lda + gk];
      As[r][kk] = v;
      int kk2 = idx >> 6, cc = idx & 63;
      int gk2 = k0 + kk2, gn = n0 + cc;
      Bs[kk2][cc] = (gk2 < K && gn < N) ? Bm[(size_t)gk2 * ldb + gn] : 0.f;
    }
    __syncthreads();
#pragma unroll
    for (int kk = 0; kk < 16; ++kk)
#pragma unroll
      for (int i = 0; i < 4; ++i)
#pragma unroll
        for (int j = 0; j < 4; ++j)
          acc[i][j] += As[ty * 4 + i][kk] * Bs[kk][tx * 4 + j];
    __syncthreads();
  }
#pragma unroll
  for (int i = 0; i < 4; ++i)
#pragma unroll
    for (int j = 0; j < 4; ++j) {
      int gm = m0 + ty * 4 + i, gn = n0 + tx * 4 + j;
      if (gm < M && gn < N) C[(size_t)gm * ldc + gn] = acc[i][j];
    }
}

// p[row] = relu(dot(Wp1[row,:], ec_flat) + bp1[row]), row < 512, K = 129600
__global__ __launch_bounds__(512) void gemv_p(const float* __restrict__ Wp1,
                                              const float* __restrict__ ec,
                                              const float* __restrict__ bp1,
                                              float* __restrict__ p) {
  int row = blockIdx.x;
  int t = threadIdx.x;
  const float4* w = (const float4*)(Wp1 + (size_t)row * 129600);
  const float4* e = (const float4*)ec;
  float s = 0.f;
  for (int i = t; i < 32400; i += 512) {
    float4 a = w[i], b = e[i];
    s += a.x * b.x + a.y * b.y + a.z * b.z + a.w * b.w;
  }
  for (int o = 32; o; o >>= 1) s += __shfl_down(s, o);
  __shared__ float redw[8];
  if ((t & 63) == 0) redw[t >> 6] = s;
  __syncthreads();
  if (t == 0) {
    float tot = 0.f;
#pragma unroll
    for (int i = 0; i < 8; ++i) tot += redw[i];
    p[row] = fmaxf(tot + bp1[row], 0.f);
  }
}

// znpi1[j] = bp2[j] + sum_k p[k] * Wp2[j*512+k], j < 128
__global__ void gemv_z(const float* __restrict__ p, const float* __restrict__ Wp2,
                       const float* __restrict__ bp2, float* __restrict__ znpi1) {
  __shared__ float pl[512];
  int t = threadIdx.x;
  pl[t] = p[t];
  pl[t + 256] = p[t + 256];
  __syncthreads();
  if (t < 128) {
    float s = bp2[t];
    const float* w = Wp2 + (size_t)t * 512;
    for (int k = 0; k < 512; ++k) s += pl[k] * w[k];
    znpi1[t] = s;
  }
}

// ---------------------------------------------------------------------------
extern "C" void kernel_launch(void* const* d_in, const int* in_sizes, int n_in,
                              void* d_out, int out_size, void* d_ws,
                              size_t ws_size, hipStream_t stream) {
  (void)in_sizes; (void)n_in; (void)out_size; (void)ws_size;
  const float* x   = (const float*)d_in[0];   // (16384, 3, 360) -> (B, 1080)
  const float* mc  = (const float*)d_in[2];   // (16384, 200)
  const float* W1  = (const float*)d_in[3];  const float* b1  = (const float*)d_in[4];
  const float* W2  = (const float*)d_in[5];  const float* b2  = (const float*)d_in[6];
  const float* W3  = (const float*)d_in[7];
  const float* Wp1 = (const float*)d_in[9];  const float* bp1 = (const float*)d_in[10];
  const float* Wp2 = (const float*)d_in[11]; const float* bp2 = (const float*)d_in[12];
  const float* Wg1 = (const float*)d_in[13]; const float* bg1 = (const float*)d_in[14];
  const float* Wg2 = (const float*)d_in[15]; const float* bg2 = (const float*)d_in[16];
  const float* Wr1 = (const float*)d_in[17]; const float* br1 = (const float*)d_in[18];
  const float* Wr2 = (const float*)d_in[19]; const float* br2 = (const float*)d_in[20];

  float* out = (float*)d_out;
  float* o_znpi = out;                  // (B,128)
  float* o_zgeo = out + 2097152;        // (B,128)
  float* o_zn   = out + 4194304;        // (B,128)
  float* o_ec   = out + 6291456;        // (360,360)
  float* o_rec  = out + 6421056;        // (B,360)

  char* ws = (char*)d_ws;
  __bf16* a1    = (__bf16*)(ws + 0);            // (B,256) relu(h1); reused as g1
  __bf16* m1b   = (__bf16*)(ws + 8388608);      // (B,256) mask1;    reused as zn_bf16
  __bf16* m2b   = (__bf16*)(ws + 16777216);     // (B,256) mask2;    reused as r1
  float*  Gpart = (float*)(ws + 25165824);      // 16 x 256 x 256
  float*  G     = (float*)(ws + 29360128);      // 256 x 256
  float*  T     = (float*)(ws + 29622272);      // 256 x 384 (ld 384)
  float*  p512  = (float*)(ws + 30015488);      // 512
  float*  znpi1 = (float*)(ws + 30017536);      // 128
  __bf16* W1p   = (__bf16*)(ws + 30018048);     // packed weights
  __bf16* W2p   = W1p  + (size_t)34 * 16 * 512;
  __bf16* Wg1p  = W2p  + (size_t)8 * 16 * 512;
  __bf16* Wg2p  = Wg1p + (size_t)7 * 16 * 512;
  __bf16* Wr1p  = Wg2p + (size_t)8 * 8 * 512;
  __bf16* Wr2p  = Wr1p + (size_t)4 * 16 * 512;
  __bf16* g1b = a1;
  __bf16* znb = m1b;
  __bf16* r1b = m2b;

  // ---- pack weights (fragment order, bf16) ----
  pack_w<<<34 * 16, 64, 0, stream>>>(W1, W1p, 256, 1080, 16);
  pack_w<<<8 * 16, 64, 0, stream>>>(W2, W2p, 256, 256, 16);
  pack_w<<<7 * 16, 64, 0, stream>>>(Wg1, Wg1p, 256, 200, 16);
  pack_w<<<8 * 8, 64, 0, stream>>>(Wg2, Wg2p, 128, 256, 8);
  pack_w<<<4 * 16, 64, 0, stream>>>(Wr1, Wr1p, 256, 128, 16);
  pack_w<<<8 * 24, 64, 0, stream>>>(Wr2, Wr2p, 360, 256, 24);

  // ---- surrogate: h1 -> (a1, m1), h2 -> m2 ----
  gemm_mfma<true, 0><<<dim3(256, 2), 256, 0, stream>>>(
      x, 1080, 1080, 34, W1p, 16, b1, 256, a1, m1b, nullptr, nullptr, nullptr);
  gemm_mfma<false, 1><<<dim3(256, 2), 256, 0, stream>>>(
      a1, 256, 256, 8, W2p, 16, b2, 256, m2b, nullptr, nullptr, nullptr, nullptr);

  // ---- G = (m2^T @ m1) / B (split-K, exact) ----
  gemm_masks<<<dim3(4, 4, 16), 256, 0, stream>>>(m2b, m1b, Gpart);
  reduce_G<<<256, 256, 0, stream>>>(Gpart, G);

  // ---- ec = W3 @ ((W2 .* G) @ W1[:, -360:]) ----
  small_gemm<<<dim3(6, 4), 256, 0, stream>>>(W2, G, 256, W1 + 720, 1080, T, 384,
                                             256, 360, 256);
  small_gemm<<<dim3(6, 6), 256, 0, stream>>>(W3, nullptr, 256, T, 384, o_ec, 360,
                                             360, 360, 256);

  // ---- z_npi1 = relu(ec_flat @ Wp1^T + bp1) @ Wp2^T + bp2 ----
  gemv_p<<<512, 512, 0, stream>>>(Wp1, o_ec, bp1, p512);
  gemv_z<<<1, 256, 0, stream>>>(p512, Wp2, bp2, znpi1);

  // ---- geo path: g1 = relu(mc @ Wg1^T + bg1) ----
  gemm_mfma<true, 2><<<dim3(256, 2), 256, 0, stream>>>(
      mc, 200, 200, 7, Wg1p, 16, bg1, 256, g1b, nullptr, nullptr, nullptr, nullptr);

  // ---- zsum: z_geo, zn, z_npi outputs + zn_bf16 for recon ----
  gemm_mfma<false, 4><<<dim3(256, 1), 256, 0, stream>>>(
      g1b, 256, 256, 8, Wg2p, 8, bg2, 128, o_zgeo, o_zn, o_znpi, znb, znpi1);

  // ---- recon: r1 = relu(zn @ Wr1^T + br1); recon = r1 @ Wr2^T + br2 ----
  gemm_mfma<false, 2><<<dim3(256, 2), 256, 0, stream>>>(
      znb, 128, 128, 4, Wr1p, 16, br1, 256, r1b, nullptr, nullptr, nullptr, nullptr);
  gemm_mfma<false, 3><<<dim3(256, 3), 256, 0, stream>>>(
      r1b, 256, 256, 8, Wr2p, 24, br2, 360, o_rec, nullptr, nullptr, nullptr, nullptr);
}

// Round 2
// 261.840 us; speedup vs baseline: 1.2116x; 1.2116x over previous
//
#include <hip/hip_runtime.h>

typedef __bf16 bf16x8 __attribute__((ext_vector_type(8)));
typedef __bf16 bf16x4 __attribute__((ext_vector_type(4)));
typedef float  f32x4  __attribute__((ext_vector_type(4)));

__device__ __forceinline__ f32x4 mfma_bf16(bf16x8 a, bf16x8 b, f32x4 c) {
  return __builtin_amdgcn_mfma_f32_16x16x32_bf16(a, b, c, 0, 0, 0);
}
// Packed B-fragment load: Bp[((kt*NT+nt)*64+lane)*8 .. +7]
__device__ __forceinline__ bf16x8 ldB(const __bf16* Bp, int kt, int NT, int nt,
                                      int lane) {
  return *reinterpret_cast<const bf16x8*>(Bp + (((size_t)kt * NT + nt) * 64 + lane) * 8);
}

// ---------------------------------------------------------------------------
// All weight packs in ONE kernel. Segment table by blockIdx range.
// out[((kt*NT+nt)*64 + lane)*8 + e] = W[nt*16 + (lane&15)][kt*32 + (lane>>4)*8 + e]
// ---------------------------------------------------------------------------
__global__ void pack_all(const float* __restrict__ W1, const float* __restrict__ W2,
                         const float* __restrict__ Wg1, const float* __restrict__ Wg2,
                         const float* __restrict__ Wr1, const float* __restrict__ Wr2,
                         __bf16* __restrict__ W1p, __bf16* __restrict__ W2p,
                         __bf16* __restrict__ Wg1p, __bf16* __restrict__ Wg2p,
                         __bf16* __restrict__ Wr1p, __bf16* __restrict__ Wr2p) {
  int bx = blockIdx.x;
  const float* W; __bf16* out; int N, K, NT, local;
  if (bx < 544)      { W = W1;  out = W1p;  N = 256; K = 1080; NT = 16; local = bx; }
  else if (bx < 672) { W = W2;  out = W2p;  N = 256; K = 256;  NT = 16; local = bx - 544; }
  else if (bx < 784) { W = Wg1; out = Wg1p; N = 256; K = 200;  NT = 16; local = bx - 672; }
  else if (bx < 848) { W = Wg2; out = Wg2p; N = 128; K = 256;  NT = 8;  local = bx - 784; }
  else if (bx < 912) { W = Wr1; out = Wr1p; N = 256; K = 128;  NT = 16; local = bx - 848; }
  else               { W = Wr2; out = Wr2p; N = 360; K = 256;  NT = 24; local = bx - 912; }
  int nt = local % NT, kt = local / NT;
  int lane = threadIdx.x;
  int n = nt * 16 + (lane & 15);
  int k0 = kt * 32 + (lane >> 4) * 8;
  bf16x8 v;
#pragma unroll
  for (int e = 0; e < 8; ++e) {
    int k = k0 + e;
    float xv = (n < N && k < K) ? W[(size_t)n * K + k] : 0.f;
    v[e] = (__bf16)xv;
  }
  *reinterpret_cast<bf16x8*>(out + ((size_t)local * 64 + lane) * 8) = v;
}

// ---------------------------------------------------------------------------
// Fused surrogate: h1 = x@W1^T+b1 (K=1080), m1 = h1>0; relu(h1) kept in LDS;
// h2 = relu(h1)@W2^T+b2, m2 = h2>0.  Tile 32 x 256 (full N), 4 waves, grid 512.
// ---------------------------------------------------------------------------
__global__ __launch_bounds__(256) void h1h2_fused(
    const float* __restrict__ x, const __bf16* __restrict__ W1p,
    const float* __restrict__ b1, const __bf16* __restrict__ W2p,
    const float* __restrict__ b2, __bf16* __restrict__ m1b,
    __bf16* __restrict__ m2b) {
  __shared__ __bf16 Alds[32][40];    // staging tile (stride 80B, ~2-way banks)
  __shared__ __bf16 h1s[32][264];    // relu(h1); stride 528B = 16B-aligned, 132 dw
  int tid = threadIdx.x;
  int lane = tid & 63, wid = tid >> 6;
  int rowBase = blockIdx.x * 32;
  int sr = tid >> 3, sc = (tid & 7) * 4;
  const float* aSrc = x + (size_t)(rowBase + sr) * 1080;
  f32x4 acc[2][4] = {};
  // depth-2 register prefetch (T14-lite)
  float4 ld0 = *(const float4*)(aSrc + sc);
  float4 ld1 = *(const float4*)(aSrc + 32 + sc);
  for (int kt = 0; kt < 34; ++kt) {
    bf16x4 w4;
    w4[0] = (__bf16)ld0.x; w4[1] = (__bf16)ld0.y;
    w4[2] = (__bf16)ld0.z; w4[3] = (__bf16)ld0.w;
    *reinterpret_cast<bf16x4*>(&Alds[sr][sc]) = w4;
    __syncthreads();
    ld0 = ld1;
    if (kt + 2 < 34) {
      int gk = (kt + 2) * 32 + sc;
      ld1 = (gk < 1080) ? *(const float4*)(aSrc + gk) : make_float4(0.f, 0.f, 0.f, 0.f);
    }
    int arow = lane & 15, ak = (lane >> 4) * 8;
    bf16x8 a0 = *reinterpret_cast<const bf16x8*>(&Alds[arow][ak]);
    bf16x8 a1 = *reinterpret_cast<const bf16x8*>(&Alds[arow + 16][ak]);
#pragma unroll
    for (int n = 0; n < 4; ++n) {
      bf16x8 bv = ldB(W1p, kt, 16, wid * 4 + n, lane);
      acc[0][n] = mfma_bf16(a0, bv, acc[0][n]);
      acc[1][n] = mfma_bf16(a1, bv, acc[1][n]);
    }
    __syncthreads();
  }
  int q4 = (lane >> 4) * 4;
#pragma unroll
  for (int m = 0; m < 2; ++m)
#pragma unroll
    for (int n = 0; n < 4; ++n) {
      int col = wid * 64 + n * 16 + (lane & 15);
      float bb = b1[col];
#pragma unroll
      for (int j = 0; j < 4; ++j) {
        int rl = m * 16 + q4 + j;
        float h = acc[m][n][j] + bb;
        m1b[(size_t)(rowBase + rl) * 256 + col] = (__bf16)(h > 0.f ? 1.f : 0.f);
        h1s[rl][col] = (__bf16)fmaxf(h, 0.f);
      }
    }
  __syncthreads();
  // ---- h2 phase: K=256 from LDS, barrier-free ----
  f32x4 acc2[2][4] = {};
#pragma unroll
  for (int ks = 0; ks < 8; ++ks) {
    int arow = lane & 15, ak = ks * 32 + (lane >> 4) * 8;
    bf16x8 a0 = *reinterpret_cast<const bf16x8*>(&h1s[arow][ak]);
    bf16x8 a1 = *reinterpret_cast<const bf16x8*>(&h1s[arow + 16][ak]);
#pragma unroll
    for (int n = 0; n < 4; ++n) {
      bf16x8 bv = ldB(W2p, ks, 16, wid * 4 + n, lane);
      acc2[0][n] = mfma_bf16(a0, bv, acc2[0][n]);
      acc2[1][n] = mfma_bf16(a1, bv, acc2[1][n]);
    }
  }
#pragma unroll
  for (int m = 0; m < 2; ++m)
#pragma unroll
    for (int n = 0; n < 4; ++n) {
      int col = wid * 64 + n * 16 + (lane & 15);
      float bb = b2[col];
#pragma unroll
      for (int j = 0; j < 4; ++j) {
        int rl = m * 16 + q4 + j;
        float h = acc2[m][n][j] + bb;
        m2b[(size_t)(rowBase + rl) * 256 + col] = (__bf16)(h > 0.f ? 1.f : 0.f);
      }
    }
}

// ---------------------------------------------------------------------------
// Gpart[z] = m2[chunk]^T @ m1[chunk] (64x64 tile). XOR-swizzled transpose
// staging: store/load col ^ (((row>>3)&3)<<3)  -> 16-way conflict becomes ~2-way.
// ---------------------------------------------------------------------------
__global__ __launch_bounds__(256) void gemm_masks(
    const __bf16* __restrict__ m2, const __bf16* __restrict__ m1,
    float* __restrict__ Gpart) {
  __shared__ __bf16 Aft[64][40];
  __shared__ __bf16 Bft[64][40];
  int tid = threadIdx.x;
  int lane = tid & 63, wid = tid >> 6;
  int wr = wid >> 1, wc = wid & 1;
  int ibase = blockIdx.x * 64, jbase = blockIdx.y * 64;
  int b0 = blockIdx.z * 1024;
  int skk = tid >> 3, si0 = (tid & 7) * 8;
  f32x4 acc[2][2] = {};
  for (int c = 0; c < 32; ++c) {
    int bb = b0 + c * 32 + skk;
    bf16x8 va = *reinterpret_cast<const bf16x8*>(m2 + (size_t)bb * 256 + ibase + si0);
    bf16x8 vb = *reinterpret_cast<const bf16x8*>(m1 + (size_t)bb * 256 + jbase + si0);
#pragma unroll
    for (int e = 0; e < 8; ++e) {
      int r = si0 + e;
      int cc = skk ^ (((r >> 3) & 3) << 3);
      Aft[r][cc] = va[e];
      Bft[r][cc] = vb[e];
    }
    __syncthreads();
    int ar = wr * 32 + (lane & 15);
    int br = wc * 32 + (lane & 15);
    int k8 = (lane >> 4) * 8;
    bf16x8 a0 = *reinterpret_cast<const bf16x8*>(&Aft[ar][k8 ^ (((ar >> 3) & 3) << 3)]);
    bf16x8 a1 = *reinterpret_cast<const bf16x8*>(
        &Aft[ar + 16][k8 ^ ((((ar + 16) >> 3) & 3) << 3)]);
    bf16x8 bv0 = *reinterpret_cast<const bf16x8*>(&Bft[br][k8 ^ (((br >> 3) & 3) << 3)]);
    bf16x8 bv1 = *reinterpret_cast<const bf16x8*>(
        &Bft[br + 16][k8 ^ ((((br + 16) >> 3) & 3) << 3)]);
    acc[0][0] = mfma_bf16(a0, bv0, acc[0][0]);
    acc[0][1] = mfma_bf16(a0, bv1, acc[0][1]);
    acc[1][0] = mfma_bf16(a1, bv0, acc[1][0]);
    acc[1][1] = mfma_bf16(a1, bv1, acc[1][1]);
    __syncthreads();
  }
  float* dst = Gpart + (size_t)blockIdx.z * 65536;
  int q4 = (lane >> 4) * 4;
#pragma unroll
  for (int m = 0; m < 2; ++m)
#pragma unroll
    for (int n = 0; n < 2; ++n)
#pragma unroll
      for (int j = 0; j < 4; ++j) {
        int gi = ibase + wr * 32 + m * 16 + q4 + j;
        int gj = jbase + wc * 32 + n * 16 + (lane & 15);
        dst[(size_t)gi * 256 + gj] = acc[m][n][j];
      }
}

__global__ void reduce_G(const float* __restrict__ Gpart, float* __restrict__ G) {
  int i = blockIdx.x * 256 + threadIdx.x;
  float s = 0.f;
#pragma unroll
  for (int z = 0; z < 16; ++z) s += Gpart[(size_t)z * 65536 + i];
  G[i] = s * (1.f / 16384.f);
}

// ---------------------------------------------------------------------------
// Small f32 GEMM: C[MxN] = (A .* A2) @ B (row-major), 64x64 tile.
// ---------------------------------------------------------------------------
__global__ __launch_bounds__(256) void small_gemm(
    const float* __restrict__ A, const float* __restrict__ A2, int lda,
    const float* __restrict__ Bm, int ldb, float* __restrict__ C, int ldc,
    int M, int N, int K) {
  __shared__ float As[64][17];
  __shared__ float Bs[16][65];
  int t = threadIdx.x;
  int tx = t & 15, ty = t >> 4;
  int m0 = blockIdx.y * 64, n0 = blockIdx.x * 64;
  float acc[4][4] = {};
  for (int k0 = 0; k0 < K; k0 += 16) {
#pragma unroll
    for (int i = 0; i < 4; ++i) {
      int idx = t * 4 + i;
      int r = idx >> 4, kk = idx & 15;
      int gm = m0 + r, gk = k0 + kk;
      float v = (gm < M && gk < K) ? A[(size_t)gm * lda + gk] : 0.f;
      if (A2 && gm < M && gk < K) v *= A2[(size_t)gm * lda + gk];
      As[r][kk] = v;
      int kk2 = idx >> 6, cc = idx & 63;
      int gk2 = k0 + kk2, gn = n0 + cc;
      Bs[kk2][cc] = (gk2 < K && gn < N) ? Bm[(size_t)gk2 * ldb + gn] : 0.f;
    }
    __syncthreads();
#pragma unroll
    for (int kk = 0; kk < 16; ++kk)
#pragma unroll
      for (int i = 0; i < 4; ++i)
#pragma unroll
        for (int j = 0; j < 4; ++j)
          acc[i][j] += As[ty * 4 + i][kk] * Bs[kk][tx * 4 + j];
    __syncthreads();
  }
#pragma unroll
  for (int i = 0; i < 4; ++i)
#pragma unroll
    for (int j = 0; j < 4; ++j) {
      int gm = m0 + ty * 4 + i, gn = n0 + tx * 4 + j;
      if (gm < M && gn < N) C[(size_t)gm * ldc + gn] = acc[i][j];
    }
}

// ---------------------------------------------------------------------------
// Fused: blocks 0..511 -> gemv_p (HBM-bound Wp1 read);
//        blocks 512..767 -> g1 = relu(mc@Wg1^T+bg1), tile 64x256 (MFMA-bound).
// The GEMM rides under the 265 MB Wp1 stream for free overlap.
// ---------------------------------------------------------------------------
__global__ __launch_bounds__(512) void p_and_g1(
    const float* __restrict__ Wp1, const float* __restrict__ ec,
    const float* __restrict__ bp1, float* __restrict__ p,
    const float* __restrict__ mc, const __bf16* __restrict__ Wg1p,
    const float* __restrict__ bg1, __bf16* __restrict__ g1b) {
  __shared__ __bf16 Alds[64][40];
  __shared__ float redw[8];
  int t = threadIdx.x;
  if (blockIdx.x < 512) {
    int row = blockIdx.x;
    const float4* w = (const float4*)(Wp1 + (size_t)row * 129600);
    const float4* e = (const float4*)ec;
    float s = 0.f;
    for (int i = t; i < 32400; i += 512) {
      float4 a = w[i], b = e[i];
      s += a.x * b.x + a.y * b.y + a.z * b.z + a.w * b.w;
    }
    for (int o = 32; o; o >>= 1) s += __shfl_down(s, o);
    if ((t & 63) == 0) redw[t >> 6] = s;
    __syncthreads();
    if (t == 0) {
      float tot = 0.f;
#pragma unroll
      for (int i = 0; i < 8; ++i) tot += redw[i];
      p[row] = fmaxf(tot + bp1[row], 0.f);
    }
  } else {
    int lane = t & 63, wid = t >> 6;
    int wr = wid >> 2, wc = wid & 3;
    int rowBase = (blockIdx.x - 512) * 64;
    int sr = t >> 3, sc = (t & 7) * 4;
    const float* aSrc = mc + (size_t)(rowBase + sr) * 200;
    f32x4 acc[2][4] = {};
    for (int kt = 0; kt < 7; ++kt) {
      int gk = kt * 32 + sc;
      bf16x4 w4;
      if (gk < 200) {
        float4 v = *(const float4*)(aSrc + gk);
        w4[0] = (__bf16)v.x; w4[1] = (__bf16)v.y;
        w4[2] = (__bf16)v.z; w4[3] = (__bf16)v.w;
      } else {
        w4[0] = w4[1] = w4[2] = w4[3] = (__bf16)0.f;
      }
      *reinterpret_cast<bf16x4*>(&Alds[sr][sc]) = w4;
      __syncthreads();
      int arow = wr * 32 + (lane & 15), ak = (lane >> 4) * 8;
      bf16x8 a0 = *reinterpret_cast<const bf16x8*>(&Alds[arow][ak]);
      bf16x8 a1 = *reinterpret_cast<const bf16x8*>(&Alds[arow + 16][ak]);
#pragma unroll
      for (int n = 0; n < 4; ++n) {
        bf16x8 bv = ldB(Wg1p, kt, 16, wc * 4 + n, lane);
        acc[0][n] = mfma_bf16(a0, bv, acc[0][n]);
        acc[1][n] = mfma_bf16(a1, bv, acc[1][n]);
      }
      __syncthreads();
    }
    int q4 = (lane >> 4) * 4;
#pragma unroll
    for (int m = 0; m < 2; ++m)
#pragma unroll
      for (int n = 0; n < 4; ++n) {
        int col = wc * 64 + n * 16 + (lane & 15);
        float bb = bg1[col];
#pragma unroll
        for (int j = 0; j < 4; ++j) {
          int rl = wr * 32 + m * 16 + q4 + j;
          g1b[(size_t)(rowBase + rl) * 256 + col] =
              (__bf16)fmaxf(acc[m][n][j] + bb, 0.f);
        }
      }
  }
}

// znpi1[j] = bp2[j] + sum_k p[k]*Wp2[j*512+k]
__global__ void gemv_z(const float* __restrict__ p, const float* __restrict__ Wp2,
                       const float* __restrict__ bp2, float* __restrict__ znpi1) {
  __shared__ float pl[512];
  int t = threadIdx.x;
  pl[t] = p[t];
  pl[t + 256] = p[t + 256];
  __syncthreads();
  if (t < 128) {
    float s = bp2[t];
    const float* w = Wp2 + (size_t)t * 512;
    for (int k = 0; k < 512; ++k) s += pl[k] * w[k];
    znpi1[t] = s;
  }
}

// ---------------------------------------------------------------------------
// Mega tail: z_geo = g1@Wg2^T+bg2; zsum=z_geo+z_npi; zn=normalize(zsum);
// r1 = relu(zn@Wr1^T+br1); recon = r1@Wr2^T+br2. One block = 64 rows, 8 waves.
// zn and r1 live in LDS; r1S aliases the (dead) g1 staging slab.
// ---------------------------------------------------------------------------
__global__ __launch_bounds__(512) void mega_tail(
    const __bf16* __restrict__ g1b, const __bf16* __restrict__ Wg2p,
    const float* __restrict__ bg2, const float* __restrict__ znpi1,
    const __bf16* __restrict__ Wr1p, const float* __restrict__ br1,
    const __bf16* __restrict__ Wr2p, const float* __restrict__ br2,
    float* __restrict__ o_zgeo, float* __restrict__ o_znpi,
    float* __restrict__ o_zn, float* __restrict__ o_rec) {
  __shared__ __align__(16) char smem[64 * 264 * 2 + 64 * 136 * 2];
  __bf16 (*Abig)[264] = (__bf16(*)[264])smem;                 // g1 slab / r1S
  __bf16 (*r1S)[264] = (__bf16(*)[264])smem;
  __bf16 (*znS)[136] = (__bf16(*)[136])(smem + 64 * 264 * 2);
  __shared__ float red[4][64];
  int tid = threadIdx.x;
  int lane = tid & 63, wid = tid >> 6;
  int wr = wid >> 2, wc = wid & 3;
  int rowBase = blockIdx.x * 64;
  int q4 = (lane >> 4) * 4;
  {  // stage 64x256 g1 slab once
    int r = tid >> 3, c0 = (tid & 7) * 32;
    const __bf16* src = g1b + (size_t)(rowBase + r) * 256 + c0;
#pragma unroll
    for (int i = 0; i < 4; ++i)
      *reinterpret_cast<bf16x8*>(&Abig[r][c0 + i * 8]) =
          *reinterpret_cast<const bf16x8*>(src + i * 8);
  }
  __syncthreads();
  // ---- phase A: z_geo + zsum + norm ----
  float zs[2][2][4];
  {
    f32x4 acc[2][2] = {};
#pragma unroll
    for (int ks = 0; ks < 8; ++ks) {
      int arow = wr * 32 + (lane & 15), ak = ks * 32 + (lane >> 4) * 8;
      bf16x8 a0 = *reinterpret_cast<const bf16x8*>(&Abig[arow][ak]);
      bf16x8 a1 = *reinterpret_cast<const bf16x8*>(&Abig[arow + 16][ak]);
#pragma unroll
      for (int n = 0; n < 2; ++n) {
        bf16x8 bv = ldB(Wg2p, ks, 8, wc * 2 + n, lane);
        acc[0][n] = mfma_bf16(a0, bv, acc[0][n]);
        acc[1][n] = mfma_bf16(a1, bv, acc[1][n]);
      }
    }
#pragma unroll
    for (int m = 0; m < 2; ++m)
#pragma unroll
      for (int n = 0; n < 2; ++n) {
        int col = wc * 32 + n * 16 + (lane & 15);
        float bb = bg2[col], zv = znpi1[col];
#pragma unroll
        for (int j = 0; j < 4; ++j) {
          int row = rowBase + wr * 32 + m * 16 + q4 + j;
          float zg = acc[m][n][j] + bb;
          o_zgeo[(size_t)row * 128 + col] = zg;
          o_znpi[(size_t)row * 128 + col] = zv;
          zs[m][n][j] = zg + zv;
        }
      }
#pragma unroll
    for (int m = 0; m < 2; ++m)
#pragma unroll
      for (int j = 0; j < 4; ++j) {
        float pp = zs[m][0][j] * zs[m][0][j] + zs[m][1][j] * zs[m][1][j];
        pp += __shfl_xor(pp, 1);
        pp += __shfl_xor(pp, 2);
        pp += __shfl_xor(pp, 4);
        pp += __shfl_xor(pp, 8);
        if ((lane & 15) == 0) red[wc][wr * 32 + m * 16 + q4 + j] = pp;
      }
    __syncthreads();
#pragma unroll
    for (int m = 0; m < 2; ++m)
#pragma unroll
      for (int n = 0; n < 2; ++n) {
        int col = wc * 32 + n * 16 + (lane & 15);
#pragma unroll
        for (int j = 0; j < 4; ++j) {
          int rl = wr * 32 + m * 16 + q4 + j;
          float ss = red[0][rl] + red[1][rl] + red[2][rl] + red[3][rl];
          float rn = 1.f / fmaxf(sqrtf(ss), 1e-12f);
          float z = zs[m][n][j] * rn;
          o_zn[(size_t)(rowBase + rl) * 128 + col] = z;
          znS[rl][col] = (__bf16)z;
        }
      }
  }
  __syncthreads();  // znS ready; all waves past phase-A Abig reads
  // ---- phase B: r1 = relu(zn@Wr1^T+br1) -> r1S (aliases Abig) ----
  {
    f32x4 acc[2][4] = {};
#pragma unroll
    for (int ks = 0; ks < 4; ++ks) {
      int arow = wr * 32 + (lane & 15), ak = ks * 32 + (lane >> 4) * 8;
      bf16x8 a0 = *reinterpret_cast<const bf16x8*>(&znS[arow][ak]);
      bf16x8 a1 = *reinterpret_cast<const bf16x8*>(&znS[arow + 16][ak]);
#pragma unroll
      for (int n = 0; n < 4; ++n) {
        bf16x8 bv = ldB(Wr1p, ks, 16, wc * 4 + n, lane);
        acc[0][n] = mfma_bf16(a0, bv, acc[0][n]);
        acc[1][n] = mfma_bf16(a1, bv, acc[1][n]);
      }
    }
#pragma unroll
    for (int m = 0; m < 2; ++m)
#pragma unroll
      for (int n = 0; n < 4; ++n) {
        int col = wc * 64 + n * 16 + (lane & 15);
        float bb = br1[col];
#pragma unroll
        for (int j = 0; j < 4; ++j) {
          int rl = wr * 32 + m * 16 + q4 + j;
          r1S[rl][col] = (__bf16)fmaxf(acc[m][n][j] + bb, 0.f);
        }
      }
  }
  __syncthreads();  // r1S ready
  // ---- phase C: recon = r1@Wr2^T+br2 (N=384 padded, store cols<360) ----
  {
    f32x4 acc[2][6] = {};
#pragma unroll
    for (int ks = 0; ks < 8; ++ks) {
      int arow = wr * 32 + (lane & 15), ak = ks * 32 + (lane >> 4) * 8;
      bf16x8 a0 = *reinterpret_cast<const bf16x8*>(&r1S[arow][ak]);
      bf16x8 a1 = *reinterpret_cast<const bf16x8*>(&r1S[arow + 16][ak]);
#pragma unroll
      for (int n = 0; n < 6; ++n) {
        bf16x8 bv = ldB(Wr2p, ks, 24, wc * 6 + n, lane);
        acc[0][n] = mfma_bf16(a0, bv, acc[0][n]);
        acc[1][n] = mfma_bf16(a1, bv, acc[1][n]);
      }
    }
#pragma unroll
    for (int m = 0; m < 2; ++m)
#pragma unroll
      for (int n = 0; n < 6; ++n) {
        int col = wc * 96 + n * 16 + (lane & 15);
        if (col < 360) {
          float bb = br2[col];
#pragma unroll
          for (int j = 0; j < 4; ++j) {
            int rl = wr * 32 + m * 16 + q4 + j;
            o_rec[(size_t)(rowBase + rl) * 360 + col] = acc[m][n][j] + bb;
          }
        }
      }
  }
}

// ---------------------------------------------------------------------------
extern "C" void kernel_launch(void* const* d_in, const int* in_sizes, int n_in,
                              void* d_out, int out_size, void* d_ws,
                              size_t ws_size, hipStream_t stream) {
  (void)in_sizes; (void)n_in; (void)out_size; (void)ws_size;
  const float* x   = (const float*)d_in[0];
  const float* mc  = (const float*)d_in[2];
  const float* W1  = (const float*)d_in[3];  const float* b1  = (const float*)d_in[4];
  const float* W2  = (const float*)d_in[5];  const float* b2  = (const float*)d_in[6];
  const float* W3  = (const float*)d_in[7];
  const float* Wp1 = (const float*)d_in[9];  const float* bp1 = (const float*)d_in[10];
  const float* Wp2 = (const float*)d_in[11]; const float* bp2 = (const float*)d_in[12];
  const float* Wg1 = (const float*)d_in[13]; const float* bg1 = (const float*)d_in[14];
  const float* Wg2 = (const float*)d_in[15]; const float* bg2 = (const float*)d_in[16];
  const float* Wr1 = (const float*)d_in[17]; const float* br1 = (const float*)d_in[18];
  const float* Wr2 = (const float*)d_in[19]; const float* br2 = (const float*)d_in[20];

  float* out = (float*)d_out;
  float* o_znpi = out;                  // (B,128)
  float* o_zgeo = out + 2097152;        // (B,128)
  float* o_zn   = out + 4194304;        // (B,128)
  float* o_ec   = out + 6291456;        // (360,360)
  float* o_rec  = out + 6421056;        // (B,360)

  char* ws = (char*)d_ws;
  __bf16* m1b   = (__bf16*)(ws + 0);            // (B,256)
  __bf16* m2b   = (__bf16*)(ws + 8388608);      // (B,256)
  __bf16* g1b   = (__bf16*)(ws + 16777216);     // (B,256)
  float*  Gpart = (float*)(ws + 25165824);      // 16 x 256 x 256
  float*  G     = (float*)(ws + 29360128);      // 256 x 256
  float*  T     = (float*)(ws + 29622272);      // 256 x 384
  float*  p512  = (float*)(ws + 30015488);      // 512
  float*  znpi1 = (float*)(ws + 30017536);      // 128
  __bf16* W1p   = (__bf16*)(ws + 30018048);
  __bf16* W2p   = W1p  + (size_t)544 * 512;
  __bf16* Wg1p  = W2p  + (size_t)128 * 512;
  __bf16* Wg2p  = Wg1p + (size_t)112 * 512;
  __bf16* Wr1p  = Wg2p + (size_t)64 * 512;
  __bf16* Wr2p  = Wr1p + (size_t)64 * 512;

  pack_all<<<1104, 64, 0, stream>>>(W1, W2, Wg1, Wg2, Wr1, Wr2,
                                    W1p, W2p, Wg1p, Wg2p, Wr1p, Wr2p);
  h1h2_fused<<<512, 256, 0, stream>>>(x, W1p, b1, W2p, b2, m1b, m2b);
  gemm_masks<<<dim3(4, 4, 16), 256, 0, stream>>>(m2b, m1b, Gpart);
  reduce_G<<<256, 256, 0, stream>>>(Gpart, G);
  small_gemm<<<dim3(6, 4), 256, 0, stream>>>(W2, G, 256, W1 + 720, 1080, T, 384,
                                             256, 360, 256);
  small_gemm<<<dim3(6, 6), 256, 0, stream>>>(W3, nullptr, 256, T, 384, o_ec, 360,
                                             360, 360, 256);
  p_and_g1<<<768, 512, 0, stream>>>(Wp1, o_ec, bp1, p512, mc, Wg1p, bg1, g1b);
  gemv_z<<<1, 256, 0, stream>>>(p512, Wp2, bp2, znpi1);
  mega_tail<<<256, 512, 0, stream>>>(g1b, Wg2p, bg2, znpi1, Wr1p, br1, Wr2p, br2,
                                     o_zgeo, o_znpi, o_zn, o_rec);
}

// Round 3
// 243.757 us; speedup vs baseline: 1.3015x; 1.0742x over previous
//
#include <hip/hip_runtime.h>

typedef __bf16 bf16x8 __attribute__((ext_vector_type(8)));
typedef __bf16 bf16x4 __attribute__((ext_vector_type(4)));
typedef float  f32x4  __attribute__((ext_vector_type(4)));

__device__ __forceinline__ f32x4 mfma_bf16(bf16x8 a, bf16x8 b, f32x4 c) {
  return __builtin_amdgcn_mfma_f32_16x16x32_bf16(a, b, c, 0, 0, 0);
}
// Packed B-fragment load: Bp[((kt*NT+nt)*64+lane)*8 .. +7]
__device__ __forceinline__ bf16x8 ldB(const __bf16* Bp, int kt, int NT, int nt,
                                      int lane) {
  return *reinterpret_cast<const bf16x8*>(Bp + (((size_t)kt * NT + nt) * 64 + lane) * 8);
}

// ---------------------------------------------------------------------------
// All weight packs in ONE kernel + zero G. Segments by blockIdx.
// pack: out[((kt*NT+nt)*64+lane)*8+e] = W[nt*16+(lane&15)][kt*32+(lane>>4)*8+e]
// ---------------------------------------------------------------------------
__global__ void pack_all(const float* __restrict__ W1, const float* __restrict__ W2,
                         const float* __restrict__ Wg1, const float* __restrict__ Wg2,
                         const float* __restrict__ Wr1, const float* __restrict__ Wr2,
                         __bf16* __restrict__ W1p, __bf16* __restrict__ W2p,
                         __bf16* __restrict__ Wg1p, __bf16* __restrict__ Wg2p,
                         __bf16* __restrict__ Wr1p, __bf16* __restrict__ Wr2p,
                         float* __restrict__ G) {
  int bx = blockIdx.x;
  int lane = threadIdx.x;
  if (bx >= 1104) {  // zero G (256x256 f32): 32 blocks x 64 thr x 8 float4
    float4* g = (float4*)G;
    int base = (bx - 1104) * 512 + lane;
#pragma unroll
    for (int i = 0; i < 8; ++i) g[base + i * 64] = make_float4(0.f, 0.f, 0.f, 0.f);
    return;
  }
  const float* W; __bf16* out; int N, K, NT, local;
  if (bx < 544)      { W = W1;  out = W1p;  N = 256; K = 1080; NT = 16; local = bx; }
  else if (bx < 672) { W = W2;  out = W2p;  N = 256; K = 256;  NT = 16; local = bx - 544; }
  else if (bx < 784) { W = Wg1; out = Wg1p; N = 256; K = 200;  NT = 16; local = bx - 672; }
  else if (bx < 848) { W = Wg2; out = Wg2p; N = 128; K = 256;  NT = 8;  local = bx - 784; }
  else if (bx < 912) { W = Wr1; out = Wr1p; N = 256; K = 128;  NT = 16; local = bx - 848; }
  else               { W = Wr2; out = Wr2p; N = 360; K = 256;  NT = 24; local = bx - 912; }
  int nt = local % NT, kt = local / NT;
  int n = nt * 16 + (lane & 15);
  int k0 = kt * 32 + (lane >> 4) * 8;
  bf16x8 v;
#pragma unroll
  for (int e = 0; e < 8; ++e) {
    int k = k0 + e;
    float xv = (n < N && k < K) ? W[(size_t)n * K + k] : 0.f;
    v[e] = (__bf16)xv;
  }
  *reinterpret_cast<bf16x8*>(out + ((size_t)local * 64 + lane) * 8) = v;
}

// ---------------------------------------------------------------------------
// Fused surrogate: h1 = x@W1^T+b1 (K=1080, K_STEP=64 -> 17 barrier pairs),
// masks written TRANSPOSED: mT[col][row], col-major for streaming masks GEMM.
// relu(h1) stays in LDS; h2 = relu(h1)@W2^T+b2. Tile 32x256, 4 waves, grid 512.
// ---------------------------------------------------------------------------
__global__ __launch_bounds__(256) void h1h2_fused(
    const float* __restrict__ x, const __bf16* __restrict__ W1p,
    const float* __restrict__ b1, const __bf16* __restrict__ W2p,
    const float* __restrict__ b2, __bf16* __restrict__ m1T,
    __bf16* __restrict__ m2T) {
  __shared__ __bf16 Alds[32][68];    // 64-wide K-slab, stride 68 (~2-way banks)
  __shared__ __bf16 h1s[32][264];    // relu(h1)
  int tid = threadIdx.x;
  int lane = tid & 63, wid = tid >> 6;
  int rowBase = blockIdx.x * 32;
  int sr = tid >> 3, sc = (tid & 7) * 8;
  const float* aSrc = x + (size_t)(rowBase + sr) * 1080;
  f32x4 acc[2][4] = {};
  float4 c0a, c0b, c1a, c1b;
  auto LD = [&](int s, float4& a, float4& b) {
    int gk = s * 64 + sc;
    if (gk < 1080) {
      a = *(const float4*)(aSrc + gk);
      b = *(const float4*)(aSrc + gk + 4);
    } else {
      a = make_float4(0.f, 0.f, 0.f, 0.f);
      b = a;
    }
  };
  LD(0, c0a, c0b);
  LD(1, c1a, c1b);
  for (int s = 0; s < 17; ++s) {
    bf16x8 w8;
    w8[0] = (__bf16)c0a.x; w8[1] = (__bf16)c0a.y; w8[2] = (__bf16)c0a.z; w8[3] = (__bf16)c0a.w;
    w8[4] = (__bf16)c0b.x; w8[5] = (__bf16)c0b.y; w8[6] = (__bf16)c0b.z; w8[7] = (__bf16)c0b.w;
    *reinterpret_cast<bf16x8*>(&Alds[sr][sc]) = w8;
    __syncthreads();
    c0a = c1a; c0b = c1b;
    if (s + 2 < 17) LD(s + 2, c1a, c1b);
    int arow = lane & 15;
#pragma unroll
    for (int ks = 0; ks < 2; ++ks) {
      int ak = ks * 32 + (lane >> 4) * 8;
      bf16x8 a0 = *reinterpret_cast<const bf16x8*>(&Alds[arow][ak]);
      bf16x8 a1 = *reinterpret_cast<const bf16x8*>(&Alds[arow + 16][ak]);
      int kt = s * 2 + ks;
#pragma unroll
      for (int n = 0; n < 4; ++n) {
        bf16x8 bv = ldB(W1p, kt, 16, wid * 4 + n, lane);
        acc[0][n] = mfma_bf16(a0, bv, acc[0][n]);
        acc[1][n] = mfma_bf16(a1, bv, acc[1][n]);
      }
    }
    __syncthreads();
  }
  int q4 = (lane >> 4) * 4;
#pragma unroll
  for (int m = 0; m < 2; ++m)
#pragma unroll
    for (int n = 0; n < 4; ++n) {
      int col = wid * 64 + n * 16 + (lane & 15);
      float bb = b1[col];
#pragma unroll
      for (int j = 0; j < 4; ++j) {
        int rl = m * 16 + q4 + j;
        float h = acc[m][n][j] + bb;
        m1T[(size_t)col * 16384 + rowBase + rl] = (__bf16)(h > 0.f ? 1.f : 0.f);
        h1s[rl][col] = (__bf16)fmaxf(h, 0.f);
      }
    }
  __syncthreads();
  // ---- h2 phase: K=256 from LDS ----
  f32x4 acc2[2][4] = {};
#pragma unroll
  for (int ks = 0; ks < 8; ++ks) {
    int arow = lane & 15, ak = ks * 32 + (lane >> 4) * 8;
    bf16x8 a0 = *reinterpret_cast<const bf16x8*>(&h1s[arow][ak]);
    bf16x8 a1 = *reinterpret_cast<const bf16x8*>(&h1s[arow + 16][ak]);
#pragma unroll
    for (int n = 0; n < 4; ++n) {
      bf16x8 bv = ldB(W2p, ks, 16, wid * 4 + n, lane);
      acc2[0][n] = mfma_bf16(a0, bv, acc2[0][n]);
      acc2[1][n] = mfma_bf16(a1, bv, acc2[1][n]);
    }
  }
#pragma unroll
  for (int m = 0; m < 2; ++m)
#pragma unroll
    for (int n = 0; n < 4; ++n) {
      int col = wid * 64 + n * 16 + (lane & 15);
      float bb = b2[col];
#pragma unroll
      for (int j = 0; j < 4; ++j) {
        int rl = m * 16 + q4 + j;
        float h = acc2[m][n][j] + bb;
        m2T[(size_t)col * 16384 + rowBase + rl] = (__bf16)(h > 0.f ? 1.f : 0.f);
      }
    }
}

// ---------------------------------------------------------------------------
// Streaming masks GEMM: G += (1/B) * m2[chunk]^T @ m1[chunk].
// Transposed mask layout -> A/B fragments are direct contiguous bf16x8 loads.
// No LDS, no barriers. Partial tiles are exact dyadic rationals -> atomicAdd
// into G is exact & deterministic.
// ---------------------------------------------------------------------------
__global__ __launch_bounds__(256) void gemm_masks(
    const __bf16* __restrict__ m2T, const __bf16* __restrict__ m1T,
    float* __restrict__ G) {
  int tid = threadIdx.x;
  int lane = tid & 63, wid = tid >> 6;
  int wr = wid >> 1, wc = wid & 1;
  int ibase = blockIdx.x * 64, jbase = blockIdx.y * 64;
  size_t b0 = (size_t)blockIdx.z * 1024 + (lane >> 4) * 8;
  const __bf16* pa0 = m2T + (size_t)(ibase + wr * 32 + (lane & 15)) * 16384 + b0;
  const __bf16* pa1 = pa0 + (size_t)16 * 16384;
  const __bf16* pb0 = m1T + (size_t)(jbase + wc * 32 + (lane & 15)) * 16384 + b0;
  const __bf16* pb1 = pb0 + (size_t)16 * 16384;
  f32x4 acc[2][2] = {};
#pragma unroll 4
  for (int c = 0; c < 32; ++c) {
    bf16x8 a0 = *reinterpret_cast<const bf16x8*>(pa0 + c * 32);
    bf16x8 a1 = *reinterpret_cast<const bf16x8*>(pa1 + c * 32);
    bf16x8 bv0 = *reinterpret_cast<const bf16x8*>(pb0 + c * 32);
    bf16x8 bv1 = *reinterpret_cast<const bf16x8*>(pb1 + c * 32);
    acc[0][0] = mfma_bf16(a0, bv0, acc[0][0]);
    acc[0][1] = mfma_bf16(a0, bv1, acc[0][1]);
    acc[1][0] = mfma_bf16(a1, bv0, acc[1][0]);
    acc[1][1] = mfma_bf16(a1, bv1, acc[1][1]);
  }
  int q4 = (lane >> 4) * 4;
#pragma unroll
  for (int m = 0; m < 2; ++m)
#pragma unroll
    for (int n = 0; n < 2; ++n)
#pragma unroll
      for (int j = 0; j < 4; ++j) {
        int gi = ibase + wr * 32 + m * 16 + q4 + j;
        int gj = jbase + wc * 32 + n * 16 + (lane & 15);
        atomicAdd(&G[(size_t)gi * 256 + gj], acc[m][n][j] * (1.f / 16384.f));
      }
}

// ---------------------------------------------------------------------------
// Small f32 GEMM: C[MxN] = (A .* A2) @ B (row-major), 64x64 tile.
// ---------------------------------------------------------------------------
__global__ __launch_bounds__(256) void small_gemm(
    const float* __restrict__ A, const float* __restrict__ A2, int lda,
    const float* __restrict__ Bm, int ldb, float* __restrict__ C, int ldc,
    int M, int N, int K) {
  __shared__ float As[64][17];
  __shared__ float Bs[16][65];
  int t = threadIdx.x;
  int tx = t & 15, ty = t >> 4;
  int m0 = blockIdx.y * 64, n0 = blockIdx.x * 64;
  float acc[4][4] = {};
  for (int k0 = 0; k0 < K; k0 += 16) {
#pragma unroll
    for (int i = 0; i < 4; ++i) {
      int idx = t * 4 + i;
      int r = idx >> 4, kk = idx & 15;
      int gm = m0 + r, gk = k0 + kk;
      float v = (gm < M && gk < K) ? A[(size_t)gm * lda + gk] : 0.f;
      if (A2 && gm < M && gk < K) v *= A2[(size_t)gm * lda + gk];
      As[r][kk] = v;
      int kk2 = idx >> 6, cc = idx & 63;
      int gk2 = k0 + kk2, gn = n0 + cc;
      Bs[kk2][cc] = (gk2 < K && gn < N) ? Bm[(size_t)gk2 * ldb + gn] : 0.f;
    }
    __syncthreads();
#pragma unroll
    for (int kk = 0; kk < 16; ++kk)
#pragma unroll
      for (int i = 0; i < 4; ++i)
#pragma unroll
        for (int j = 0; j < 4; ++j)
          acc[i][j] += As[ty * 4 + i][kk] * Bs[kk][tx * 4 + j];
    __syncthreads();
  }
#pragma unroll
  for (int i = 0; i < 4; ++i)
#pragma unroll
    for (int j = 0; j < 4; ++j) {
      int gm = m0 + ty * 4 + i, gn = n0 + tx * 4 + j;
      if (gm < M && gn < N) C[(size_t)gm * ldc + gn] = acc[i][j];
    }
}

// ---------------------------------------------------------------------------
// Fused: blocks 0..511 -> gemv_p (HBM-bound Wp1 read);
//        blocks 512..767 -> g1 = relu(mc@Wg1^T+bg1) in LDS, then
//                           o_zgeo = g1@Wg2^T+bg2 (rides free under Wp1 stream).
// ---------------------------------------------------------------------------
__global__ __launch_bounds__(512) void p_and_g1(
    const float* __restrict__ Wp1, const float* __restrict__ ec,
    const float* __restrict__ bp1, float* __restrict__ p,
    const float* __restrict__ mc, const __bf16* __restrict__ Wg1p,
    const float* __restrict__ bg1, const __bf16* __restrict__ Wg2p,
    const float* __restrict__ bg2, float* __restrict__ o_zgeo) {
  __shared__ __bf16 Alds[64][40];
  __shared__ __bf16 g1S[64][264];
  __shared__ float redw[8];
  int t = threadIdx.x;
  if (blockIdx.x < 512) {
    int row = blockIdx.x;
    const float4* w = (const float4*)(Wp1 + (size_t)row * 129600);
    const float4* e = (const float4*)ec;
    float s = 0.f;
    for (int i = t; i < 32400; i += 512) {
      float4 a = w[i], b = e[i];
      s += a.x * b.x + a.y * b.y + a.z * b.z + a.w * b.w;
    }
    for (int o = 32; o; o >>= 1) s += __shfl_down(s, o);
    if ((t & 63) == 0) redw[t >> 6] = s;
    __syncthreads();
    if (t == 0) {
      float tot = 0.f;
#pragma unroll
      for (int i = 0; i < 8; ++i) tot += redw[i];
      p[row] = fmaxf(tot + bp1[row], 0.f);
    }
  } else {
    int lane = t & 63, wid = t >> 6;
    int wr = wid >> 2, wc = wid & 3;
    int rowBase = (blockIdx.x - 512) * 64;
    int sr = t >> 3, sc = (t & 7) * 4;
    const float* aSrc = mc + (size_t)(rowBase + sr) * 200;
    int q4 = (lane >> 4) * 4;
    f32x4 acc[2][4] = {};
    for (int kt = 0; kt < 7; ++kt) {
      int gk = kt * 32 + sc;
      bf16x4 w4;
      if (gk < 200) {
        float4 v = *(const float4*)(aSrc + gk);
        w4[0] = (__bf16)v.x; w4[1] = (__bf16)v.y;
        w4[2] = (__bf16)v.z; w4[3] = (__bf16)v.w;
      } else {
        w4[0] = w4[1] = w4[2] = w4[3] = (__bf16)0.f;
      }
      *reinterpret_cast<bf16x4*>(&Alds[sr][sc]) = w4;
      __syncthreads();
      int arow = wr * 32 + (lane & 15), ak = (lane >> 4) * 8;
      bf16x8 a0 = *reinterpret_cast<const bf16x8*>(&Alds[arow][ak]);
      bf16x8 a1 = *reinterpret_cast<const bf16x8*>(&Alds[arow + 16][ak]);
#pragma unroll
      for (int n = 0; n < 4; ++n) {
        bf16x8 bv = ldB(Wg1p, kt, 16, wc * 4 + n, lane);
        acc[0][n] = mfma_bf16(a0, bv, acc[0][n]);
        acc[1][n] = mfma_bf16(a1, bv, acc[1][n]);
      }
      __syncthreads();
    }
#pragma unroll
    for (int m = 0; m < 2; ++m)
#pragma unroll
      for (int n = 0; n < 4; ++n) {
        int col = wc * 64 + n * 16 + (lane & 15);
        float bb = bg1[col];
#pragma unroll
        for (int j = 0; j < 4; ++j) {
          int rl = wr * 32 + m * 16 + q4 + j;
          g1S[rl][col] = (__bf16)fmaxf(acc[m][n][j] + bb, 0.f);
        }
      }
    __syncthreads();
    // ---- zgeo = g1 @ Wg2^T + bg2 (N=128) ----
    f32x4 acc2[2][2] = {};
#pragma unroll
    for (int ks = 0; ks < 8; ++ks) {
      int arow = wr * 32 + (lane & 15), ak = ks * 32 + (lane >> 4) * 8;
      bf16x8 a0 = *reinterpret_cast<const bf16x8*>(&g1S[arow][ak]);
      bf16x8 a1 = *reinterpret_cast<const bf16x8*>(&g1S[arow + 16][ak]);
#pragma unroll
      for (int n = 0; n < 2; ++n) {
        bf16x8 bv = ldB(Wg2p, ks, 8, wc * 2 + n, lane);
        acc2[0][n] = mfma_bf16(a0, bv, acc2[0][n]);
        acc2[1][n] = mfma_bf16(a1, bv, acc2[1][n]);
      }
    }
#pragma unroll
    for (int m = 0; m < 2; ++m)
#pragma unroll
      for (int n = 0; n < 2; ++n) {
        int col = wc * 32 + n * 16 + (lane & 15);
        float bb = bg2[col];
#pragma unroll
        for (int j = 0; j < 4; ++j) {
          int row = rowBase + wr * 32 + m * 16 + q4 + j;
          o_zgeo[(size_t)row * 128 + col] = acc2[m][n][j] + bb;
        }
      }
  }
}

// znpi1[j] = bp2[j] + sum_k p[k]*Wp2[j*512+k]; 128 blocks x 64 threads
__global__ void gemv_z(const float* __restrict__ p, const float* __restrict__ Wp2,
                       const float* __restrict__ bp2, float* __restrict__ znpi1) {
  int j = blockIdx.x;
  int t = threadIdx.x;
  const float4* w = (const float4*)(Wp2 + (size_t)j * 512);
  const float4* pp = (const float4*)p;
  float4 a0 = w[t], b0 = pp[t];
  float4 a1 = w[t + 64], b1 = pp[t + 64];
  float s = a0.x * b0.x + a0.y * b0.y + a0.z * b0.z + a0.w * b0.w +
            a1.x * b1.x + a1.y * b1.y + a1.z * b1.z + a1.w * b1.w;
  for (int o = 32; o; o >>= 1) s += __shfl_down(s, o);
  if (t == 0) znpi1[j] = s + bp2[j];
}

// ---------------------------------------------------------------------------
// Tail: zsum = zgeo + znpi1; zn = normalize(zsum); r1 = relu(zn@Wr1^T+br1);
// recon = r1@Wr2^T+br2. One block = 64 rows, 8 waves. zn, r1 live in LDS.
// ---------------------------------------------------------------------------
__global__ __launch_bounds__(512) void mega_tail(
    const float* __restrict__ zgeo, const float* __restrict__ znpi1,
    const __bf16* __restrict__ Wr1p, const float* __restrict__ br1,
    const __bf16* __restrict__ Wr2p, const float* __restrict__ br2,
    float* __restrict__ o_znpi, float* __restrict__ o_zn,
    float* __restrict__ o_rec) {
  __shared__ __bf16 r1S[64][264];
  __shared__ __bf16 znS[64][136];
  __shared__ float znpiS[128];
  int tid = threadIdx.x;
  int lane = tid & 63, wid = tid >> 6;
  int wr = wid >> 2, wc = wid & 3;
  int rowBase = blockIdx.x * 64;
  int q4 = (lane >> 4) * 4;
  if (tid < 128) znpiS[tid] = znpi1[tid];
  __syncthreads();
  // ---- phase A: zsum + norm (thread group of 32 owns one row) ----
  {
    int rg = tid >> 5;          // 0..15
    int c4 = (tid & 31) * 4;    // 0..124
    float4 zp = make_float4(znpiS[c4], znpiS[c4 + 1], znpiS[c4 + 2], znpiS[c4 + 3]);
#pragma unroll
    for (int ri = 0; ri < 4; ++ri) {
      int rl = rg + ri * 16;
      int row = rowBase + rl;
      float4 zg = *(const float4*)(zgeo + (size_t)row * 128 + c4);
      float4 zs = make_float4(zg.x + zp.x, zg.y + zp.y, zg.z + zp.z, zg.w + zp.w);
      *(float4*)(o_znpi + (size_t)row * 128 + c4) = zp;
      float ss = zs.x * zs.x + zs.y * zs.y + zs.z * zs.z + zs.w * zs.w;
      ss += __shfl_xor(ss, 1);
      ss += __shfl_xor(ss, 2);
      ss += __shfl_xor(ss, 4);
      ss += __shfl_xor(ss, 8);
      ss += __shfl_xor(ss, 16);
      float rn = 1.f / fmaxf(sqrtf(ss), 1e-12f);
      float4 zn = make_float4(zs.x * rn, zs.y * rn, zs.z * rn, zs.w * rn);
      *(float4*)(o_zn + (size_t)row * 128 + c4) = zn;
      bf16x4 znb;
      znb[0] = (__bf16)zn.x; znb[1] = (__bf16)zn.y;
      znb[2] = (__bf16)zn.z; znb[3] = (__bf16)zn.w;
      *reinterpret_cast<bf16x4*>(&znS[rl][c4]) = znb;
    }
  }
  __syncthreads();
  // ---- phase B: r1 = relu(zn@Wr1^T+br1) -> r1S ----
  {
    f32x4 acc[2][4] = {};
#pragma unroll
    for (int ks = 0; ks < 4; ++ks) {
      int arow = wr * 32 + (lane & 15), ak = ks * 32 + (lane >> 4) * 8;
      bf16x8 a0 = *reinterpret_cast<const bf16x8*>(&znS[arow][ak]);
      bf16x8 a1 = *reinterpret_cast<const bf16x8*>(&znS[arow + 16][ak]);
#pragma unroll
      for (int n = 0; n < 4; ++n) {
        bf16x8 bv = ldB(Wr1p, ks, 16, wc * 4 + n, lane);
        acc[0][n] = mfma_bf16(a0, bv, acc[0][n]);
        acc[1][n] = mfma_bf16(a1, bv, acc[1][n]);
      }
    }
#pragma unroll
    for (int m = 0; m < 2; ++m)
#pragma unroll
      for (int n = 0; n < 4; ++n) {
        int col = wc * 64 + n * 16 + (lane & 15);
        float bb = br1[col];
#pragma unroll
        for (int j = 0; j < 4; ++j) {
          int rl = wr * 32 + m * 16 + q4 + j;
          r1S[rl][col] = (__bf16)fmaxf(acc[m][n][j] + bb, 0.f);
        }
      }
  }
  __syncthreads();
  // ---- phase C: recon = r1@Wr2^T+br2 (N=384 padded, store cols<360) ----
  {
    f32x4 acc[2][6] = {};
#pragma unroll
    for (int ks = 0; ks < 8; ++ks) {
      int arow = wr * 32 + (lane & 15), ak = ks * 32 + (lane >> 4) * 8;
      bf16x8 a0 = *reinterpret_cast<const bf16x8*>(&r1S[arow][ak]);
      bf16x8 a1 = *reinterpret_cast<const bf16x8*>(&r1S[arow + 16][ak]);
#pragma unroll
      for (int n = 0; n < 6; ++n) {
        bf16x8 bv = ldB(Wr2p, ks, 24, wc * 6 + n, lane);
        acc[0][n] = mfma_bf16(a0, bv, acc[0][n]);
        acc[1][n] = mfma_bf16(a1, bv, acc[1][n]);
      }
    }
#pragma unroll
    for (int m = 0; m < 2; ++m)
#pragma unroll
      for (int n = 0; n < 6; ++n) {
        int col = wc * 96 + n * 16 + (lane & 15);
        if (col < 360) {
          float bb = br2[col];
#pragma unroll
          for (int j = 0; j < 4; ++j) {
            int rl = wr * 32 + m * 16 + q4 + j;
            o_rec[(size_t)(rowBase + rl) * 360 + col] = acc[m][n][j] + bb;
          }
        }
      }
  }
}

// ---------------------------------------------------------------------------
extern "C" void kernel_launch(void* const* d_in, const int* in_sizes, int n_in,
                              void* d_out, int out_size, void* d_ws,
                              size_t ws_size, hipStream_t stream) {
  (void)in_sizes; (void)n_in; (void)out_size; (void)ws_size;
  const float* x   = (const float*)d_in[0];
  const float* mc  = (const float*)d_in[2];
  const float* W1  = (const float*)d_in[3];  const float* b1  = (const float*)d_in[4];
  const float* W2  = (const float*)d_in[5];  const float* b2  = (const float*)d_in[6];
  const float* W3  = (const float*)d_in[7];
  const float* Wp1 = (const float*)d_in[9];  const float* bp1 = (const float*)d_in[10];
  const float* Wp2 = (const float*)d_in[11]; const float* bp2 = (const float*)d_in[12];
  const float* Wg1 = (const float*)d_in[13]; const float* bg1 = (const float*)d_in[14];
  const float* Wg2 = (const float*)d_in[15]; const float* bg2 = (const float*)d_in[16];
  const float* Wr1 = (const float*)d_in[17]; const float* br1 = (const float*)d_in[18];
  const float* Wr2 = (const float*)d_in[19]; const float* br2 = (const float*)d_in[20];

  float* out = (float*)d_out;
  float* o_znpi = out;                  // (B,128)
  float* o_zgeo = out + 2097152;        // (B,128)
  float* o_zn   = out + 4194304;        // (B,128)
  float* o_ec   = out + 6291456;        // (360,360)
  float* o_rec  = out + 6421056;        // (B,360)

  char* ws = (char*)d_ws;
  __bf16* m1T   = (__bf16*)(ws + 0);            // (256, 16384) transposed mask1
  __bf16* m2T   = (__bf16*)(ws + 8388608);      // (256, 16384) transposed mask2
  float*  G     = (float*)(ws + 16777216);      // 256 x 256
  float*  T     = (float*)(ws + 17039360);      // 256 x 384
  float*  p512  = (float*)(ws + 17432576);      // 512
  float*  znpi1 = (float*)(ws + 17434624);      // 128
  __bf16* W1p   = (__bf16*)(ws + 17435648);
  __bf16* W2p   = W1p  + (size_t)544 * 512;
  __bf16* Wg1p  = W2p  + (size_t)128 * 512;
  __bf16* Wg2p  = Wg1p + (size_t)112 * 512;
  __bf16* Wr1p  = Wg2p + (size_t)64 * 512;
  __bf16* Wr2p  = Wr1p + (size_t)64 * 512;

  pack_all<<<1136, 64, 0, stream>>>(W1, W2, Wg1, Wg2, Wr1, Wr2,
                                    W1p, W2p, Wg1p, Wg2p, Wr1p, Wr2p, G);
  h1h2_fused<<<512, 256, 0, stream>>>(x, W1p, b1, W2p, b2, m1T, m2T);
  gemm_masks<<<dim3(4, 4, 16), 256, 0, stream>>>(m2T, m1T, G);
  small_gemm<<<dim3(6, 4), 256, 0, stream>>>(W2, G, 256, W1 + 720, 1080, T, 384,
                                             256, 360, 256);
  small_gemm<<<dim3(6, 6), 256, 0, stream>>>(W3, nullptr, 256, T, 384, o_ec, 360,
                                             360, 360, 256);
  p_and_g1<<<768, 512, 0, stream>>>(Wp1, o_ec, bp1, p512, mc, Wg1p, bg1,
                                    Wg2p, bg2, o_zgeo);
  gemv_z<<<128, 64, 0, stream>>>(p512, Wp2, bp2, znpi1);
  mega_tail<<<256, 512, 0, stream>>>(o_zgeo, znpi1, Wr1p, br1, Wr2p, br2,
                                     o_znpi, o_zn, o_rec);
}